// Round 6
// baseline (3016.937 us; speedup 1.0000x reference)
//
#include <hip/hip_runtime.h>
#include <cstdint>
#include <cstddef>

// NCA: x = bilinear(seed)->1024x1024 NHWC fp32; 64x [conv3x3(8->32)+gelu, conv1x1(32->8)*0.1,
// masked add]; project 8->1. Convs via mfma_f32_16x16x32_f16 implicit GEMM, OPERAND-SWAPPED:
//   conv3x3: mfma(A=W1frag, B=pixelfrag) -> D[ch(regs)][pixel(lane&15)]
//   -> each lane holds 8 hidden ch of ONE pixel = direct A-operand for conv1x1 (k''=q*8+j order)
//   conv1x1: mfma(A=h, B=W2frag) -> D[pixel(regs)][outch(lane&15)] -> direct global update.
// No LDS transpose, no dxbuf, ONE barrier per step. Biases folded into MFMA C-init.
// PRNG: jax threefry2x32 partitionable: subkey[i]=raw pair tf2x32((0,42),(0,i));
// bits[p]=o0^o1 of tf2x32(subkey,(0,p)); mask = (bits>>9) > 2^22. Ballot-packed into LDS bitmap.

#define HH 1024
#define WW 1024
#define SD 8
#define HID 32
#define TX 32
#define TY 16

typedef _Float16 f16x8 __attribute__((ext_vector_type(8)));
typedef float f32x4 __attribute__((ext_vector_type(4)));
typedef uint32_t u32x4 __attribute__((ext_vector_type(4)));

__host__ __device__ inline uint32_t rotl32(uint32_t x, int n) {
  return (x << n) | (x >> (32 - n));
}

__host__ __device__ inline void tf2x32(uint32_t k0, uint32_t k1,
                                       uint32_t x0, uint32_t x1,
                                       uint32_t& o0, uint32_t& o1) {
  uint32_t ks0 = k0, ks1 = k1, ks2 = k0 ^ k1 ^ 0x1BD11BDAu;
  x0 += ks0; x1 += ks1;
#define TFR(r) { x0 += x1; x1 = rotl32(x1, (r)); x1 ^= x0; }
  TFR(13) TFR(15) TFR(26) TFR(6)  x0 += ks1; x1 += ks2 + 1u;
  TFR(17) TFR(29) TFR(16) TFR(24) x0 += ks2; x1 += ks0 + 2u;
  TFR(13) TFR(15) TFR(26) TFR(6)  x0 += ks0; x1 += ks1 + 3u;
  TFR(17) TFR(29) TFR(16) TFR(24) x0 += ks1; x1 += ks2 + 4u;
  TFR(13) TFR(15) TFR(26) TFR(6)  x0 += ks2; x1 += ks0 + 5u;
#undef TFR
  o0 = x0; o1 = x1;
}

// gelu(x) = 0.5x + 0.5|x|*erf(|x|/sqrt2); erf via A&S 7.1.26 branchless, |err|<=1.5e-7.
__device__ inline float gelu_fast(float x) {
  const float ax = __builtin_fabsf(x);
  const float ay = 0.70710678118654752f * ax;
  const float t = __builtin_amdgcn_rcpf(fmaf(0.3275911f, ay, 1.0f));
  float p = fmaf(1.061405429f, t, -1.453152027f);
  p = fmaf(p, t, 1.421413741f);
  p = fmaf(p, t, -0.284496736f);
  p = fmaf(p, t, 0.254829592f);
  p *= t;
  const float e = __expf(-ay * ay);
  const float erfv = fmaf(-p, e, 1.0f);
  return fmaf(0.5f * ax, erfv, 0.5f * x);
}

// ---- bilinear upsample 8x8 -> 1024x1024, NHWC fp32 out ----
__global__ void init_kernel(const float* __restrict__ seed, float* __restrict__ dst) {
  int p = blockIdx.x * blockDim.x + threadIdx.x;
  if (p >= HH * WW) return;
  int y = p >> 10, x = p & 1023;
  float fy = (y + 0.5f) * (8.0f / HH) - 0.5f;
  float fx = (x + 0.5f) * (8.0f / WW) - 0.5f;
  int y0 = (int)floorf(fy); float wy = fy - (float)y0;
  int x0 = (int)floorf(fx); float wx = fx - (float)x0;
  int y0c = min(max(y0, 0), 7), y1c = min(max(y0 + 1, 0), 7);
  int x0c = min(max(x0, 0), 7), x1c = min(max(x0 + 1, 0), 7);
  float vals[8];
#pragma unroll
  for (int c = 0; c < SD; ++c) {
    const float* s = seed + c * 64;
    float v00 = s[y0c * 8 + x0c], v01 = s[y0c * 8 + x1c];
    float v10 = s[y1c * 8 + x0c], v11 = s[y1c * 8 + x1c];
    float v0 = v00 + (v01 - v00) * wx;
    float v1 = v10 + (v11 - v10) * wx;
    vals[c] = v0 + (v1 - v0) * wy;
  }
  f32x4 lo = {vals[0], vals[1], vals[2], vals[3]};
  f32x4 hi = {vals[4], vals[5], vals[6], vals[7]};
  *(f32x4*)(dst + (size_t)p * 8) = lo;
  *(f32x4*)(dst + (size_t)p * 8 + 4) = hi;
}

// ---- pack W1 (A-operand frags) and W2 (B-operand, k''-order) ----
// W1f: row n = nt*16+(lane&15) [out-ch], k = kc*32+(lane>>4)*8+j, k=tap*8+c -> tap=kc*4+q, c=j
// W2f: row n = lane&15 [out-ch, <8 valid], k'' = (lane>>4)*8+jj,
//      channel(k'') = (lane>>4)*4 + (jj&3) + ((jj>>2)<<4)
__global__ void prep_kernel(const float* __restrict__ W1, const float* __restrict__ W2,
                            _Float16* __restrict__ w1f, _Float16* __restrict__ w2f) {
  int tid = threadIdx.x;
  for (int i = tid; i < 2 * 3 * 64; i += 256) {
    int nt = i / 192, rem = i % 192;
    int kc = rem / 64, lane = rem % 64;
    int n = nt * 16 + (lane & 15);
    int tap = kc * 4 + (lane >> 4);
#pragma unroll
    for (int j = 0; j < 8; ++j) {
      float v = (tap < 9) ? W1[(n * SD + j) * 9 + tap] : 0.0f;
      w1f[i * 8 + j] = (_Float16)v;
    }
  }
  if (tid < 64) {
    int n = tid & 15, qk = tid >> 4;
#pragma unroll
    for (int jj = 0; jj < 8; ++jj) {
      int ch = qk * 4 + (jj & 3) + ((jj >> 2) << 4);
      float v = (n < 8) ? W2[n * HID + ch] : 0.0f;
      w2f[tid * 8 + jj] = (_Float16)v;
    }
  }
}

// ---- fused NCA step: one barrier, no LDS transposes ----
__global__ __launch_bounds__(256, 8) void step_kernel(
    const float* __restrict__ src, float* __restrict__ dst,
    const _Float16* __restrict__ w1f, const _Float16* __restrict__ w2f,
    const float* __restrict__ b1, const float* __restrict__ b2,
    uint32_t key0, uint32_t key1) {
  __shared__ _Float16 tile[(TY + 2) * (TX + 2) * SD];   // NHWC f16, halo +1 (9792 B)
  __shared__ uint32_t maskbits[16];                     // 512 mask bits, 1 dword per row

  const int tid = threadIdx.x;
  const int bx = blockIdx.x, by = blockIdx.y;
  const int lane = tid & 63, w = tid >> 6;
  const int m = lane & 15, q = lane >> 4;

  // ---- weight fragments + biases (global, L1-hot) — issue before barrier ----
  f16x8 af[2][3];
#pragma unroll
  for (int nt = 0; nt < 2; ++nt)
#pragma unroll
    for (int kc = 0; kc < 3; ++kc)
      af[nt][kc] = *(const f16x8*)(w1f + ((nt * 3 + kc) * 64 + lane) * 8);
  const f16x8 w2fr = *(const f16x8*)(w2f + lane * 8);
  const f32x4 b1q0 = *(const f32x4*)(b1 + q * 4);        // ch q*4+r
  const f32x4 b1q1 = *(const f32x4*)(b1 + 16 + q * 4);   // ch 16+q*4+r
  const float b2v = b2[m & 7];

  // ---- stage fp32 NHWC -> f16 NHWC LDS tile (zero pad outside) ----
  for (int i = tid; i < (TY + 2) * (TX + 2); i += 256) {
    int ly = i / (TX + 2), lx = i % (TX + 2);
    int gy = by * TY + ly - 1, gx = bx * TX + lx - 1;
    f16x8 v;
#pragma unroll
    for (int j = 0; j < 8; ++j) v[j] = (_Float16)0.0f;
    if ((unsigned)gy < HH && (unsigned)gx < WW) {
      const float* xp = src + (size_t)(gy * WW + gx) * 8;
      f32x4 lo = *(const f32x4*)xp;
      f32x4 hi = *(const f32x4*)(xp + 4);
#pragma unroll
      for (int j = 0; j < 4; ++j) { v[j] = (_Float16)lo[j]; v[4 + j] = (_Float16)hi[j]; }
    }
    *(f16x8*)&tile[i * 8] = v;
  }

  // ---- threefry masks, ballot-packed: dword per row of 32 pixels ----
#pragma unroll
  for (int it = 0; it < 2; ++it) {
    const int pl = it * 256 + tid;  // pixel-in-block, row = pl>>5
    const uint32_t gp = (uint32_t)((by * TY + (pl >> 5)) * WW + bx * TX + (pl & 31));
    uint32_t r0, r1;
    tf2x32(key0, key1, 0u, gp, r0, r1);
    const bool mb = (((r0 ^ r1) >> 9) > 0x400000u);
    const unsigned long long bal = __ballot(mb);
    if (lane == 0) {
      maskbits[it * 8 + w * 2] = (uint32_t)bal;
      maskbits[it * 8 + w * 2 + 1] = (uint32_t)(bal >> 32);
    }
  }
  __syncthreads();

  // per-lane B1 (pixel) base pointers for the 3 K-chunks (taps 9..11: zero A-rows, clamp addr)
  const _Float16* bp_[3];
#pragma unroll
  for (int kc = 0; kc < 3; ++kc) {
    int t = kc * 4 + q; if (t > 8) t = 0;
    bp_[kc] = &tile[((t / 3) * (TX + 2) + m + (t % 3)) * 8];
  }

#pragma unroll
  for (int r4 = 0; r4 < 4; ++r4) {
    const int y = w * 4 + r4;                       // local row 0..15, wave-uniform
    const uint32_t mrow = maskbits[y];              // broadcast ds_read
    const size_t rowbase = ((size_t)((by * TY + y) * WW + bx * TX)) * 8;
#pragma unroll
    for (int xh = 0; xh < 2; ++xh) {
      const int x0 = xh * 16;
      f32x4 acc0 = b1q0, acc1 = b1q1;               // bias folded into C
#pragma unroll
      for (int kc = 0; kc < 3; ++kc) {
        const f16x8 bfrag = *(const f16x8*)(bp_[kc] + (y * (TX + 2) + x0) * 8);
        acc0 = __builtin_amdgcn_mfma_f32_16x16x32_f16(af[0][kc], bfrag, acc0, 0, 0, 0);
        acc1 = __builtin_amdgcn_mfma_f32_16x16x32_f16(af[1][kc], bfrag, acc1, 0, 0, 0);
      }
      // lane now holds hidden ch {q*4+r} (acc0) and {16+q*4+r} (acc1) of pixel x0+m.
      // gelu + pack -> A2 fragment in k''=q*8+j order, no LDS round-trip.
      u32x4 a2d;
      {
        float g0 = gelu_fast(acc0[0]), g1 = gelu_fast(acc0[1]);
        float g2 = gelu_fast(acc0[2]), g3 = gelu_fast(acc0[3]);
        float g4 = gelu_fast(acc1[0]), g5 = gelu_fast(acc1[1]);
        float g6 = gelu_fast(acc1[2]), g7 = gelu_fast(acc1[3]);
        a2d[0] = __builtin_bit_cast(uint32_t, __builtin_amdgcn_cvt_pkrtz(g0, g1));
        a2d[1] = __builtin_bit_cast(uint32_t, __builtin_amdgcn_cvt_pkrtz(g2, g3));
        a2d[2] = __builtin_bit_cast(uint32_t, __builtin_amdgcn_cvt_pkrtz(g4, g5));
        a2d[3] = __builtin_bit_cast(uint32_t, __builtin_amdgcn_cvt_pkrtz(g6, g7));
      }
      const f16x8 a2 = __builtin_bit_cast(f16x8, a2d);
      f32x4 acc2 = {b2v, b2v, b2v, b2v};
      acc2 = __builtin_amdgcn_mfma_f32_16x16x32_f16(a2, w2fr, acc2, 0, 0, 0);
      // D2: lane&15 = out-ch (m<8 valid), regs = pixels x0+q*4+r. Update global directly.
      if (m < 8) {
#pragma unroll
        for (int r = 0; r < 4; ++r) {
          const int px = x0 + q * 4 + r;
          const float sel = (mrow & (1u << px)) ? 0.1f : 0.0f;  // 0.1*mask folded
          const size_t idx = rowbase + (size_t)(px * 8 + m);
          dst[idx] = fmaf(acc2[r], sel, src[idx]);
        }
      }
    }
  }
}

// ---- projection: out[p] = bp + sum_c x[p][c]*Wp[c] (NHWC) ----
__global__ void proj_kernel(const float* __restrict__ x,
                            const float* __restrict__ Wp,
                            const float* __restrict__ bp,
                            float* __restrict__ out) {
  int p = blockIdx.x * blockDim.x + threadIdx.x;
  if (p >= HH * WW) return;
  const float* xp = x + (size_t)p * 8;
  f32x4 lo = *(const f32x4*)xp;
  f32x4 hi = *(const f32x4*)(xp + 4);
  float acc = bp[0];
#pragma unroll
  for (int c = 0; c < 4; ++c) acc = fmaf(lo[c], Wp[c], acc);
#pragma unroll
  for (int c = 0; c < 4; ++c) acc = fmaf(hi[c], Wp[4 + c], acc);
  out[p] = acc;
}

extern "C" void kernel_launch(void* const* d_in, const int* in_sizes, int n_in,
                              void* d_out, int out_size, void* d_ws, size_t ws_size,
                              hipStream_t stream) {
  (void)in_sizes; (void)n_in; (void)out_size; (void)ws_size;
  const float* seed = (const float*)d_in[0];
  const float* W1   = (const float*)d_in[1];
  const float* b1   = (const float*)d_in[2];
  const float* W2   = (const float*)d_in[3];
  const float* b2   = (const float*)d_in[4];
  const float* Wp   = (const float*)d_in[5];
  const float* bp   = (const float*)d_in[6];
  float* out  = (float*)d_out;
  float* buf0 = (float*)d_ws;
  float* buf1 = buf0 + (size_t)SD * HH * WW;
  _Float16* w1f = (_Float16*)(buf1 + (size_t)SD * HH * WW);
  _Float16* w2f = w1f + 2 * 3 * 64 * 8;

  // 64 subkeys of jax.random.split(jax.random.key(42), 64) (raw pairs, no xor)
  uint32_t ka[64], kb[64];
  for (int i = 0; i < 64; ++i) tf2x32(0u, 42u, 0u, (uint32_t)i, ka[i], kb[i]);

  hipLaunchKernelGGL(prep_kernel, dim3(1), dim3(256), 0, stream, W1, W2, w1f, w2f);
  hipLaunchKernelGGL(init_kernel, dim3((HH * WW) / 256), dim3(256), 0, stream, seed, buf0);

  dim3 grid(WW / TX, HH / TY);
  float* s = buf0; float* d = buf1;
  for (int i = 0; i < 64; ++i) {
    hipLaunchKernelGGL(step_kernel, grid, dim3(256), 0, stream,
                       s, d, w1f, w2f, b1, b2, ka[i], kb[i]);
    float* t = s; s = d; d = t;
  }
  hipLaunchKernelGGL(proj_kernel, dim3((HH * WW) / 256), dim3(256), 0, stream,
                     s, Wp, bp, out);
}

// Round 7
// 1747.930 us; speedup vs baseline: 1.7260x; 1.7260x over previous
//
#include <hip/hip_runtime.h>
#include <cstdint>
#include <cstddef>

// NCA: x = bilinear(seed)->1024x1024 NHWC fp32; 64x [conv3x3(8->32)+gelu, conv1x1(32->8)*0.1,
// masked add]; project 8->1. Convs via mfma_f32_16x16x32_f16 implicit GEMM, operand-swapped:
//   conv3x3: mfma(A=W1frag, B=pixelfrag) -> D[ch(regs)][pixel(lane&15)]
//   -> each lane holds 8 hidden ch of ONE pixel = direct A-operand for conv1x1 (k''-order W2)
//   conv1x1: mfma(A=h, B=W2frag) -> D[pixel(regs)][outch(lane&15)]
// dx staged in wave-local LDS (intra-wave ds_write->ds_read, no 2nd barrier), then
// coalesced f32x4 update of the fp32 NHWC state. ONE barrier per step.
// PRNG: jax threefry2x32 partitionable: subkey[i]=raw pair tf2x32((0,42),(0,i));
// bits[p]=o0^o1 of tf2x32(subkey,(0,p)); mask = (bits>>9) > 2^22.

#define HH 1024
#define WW 1024
#define SD 8
#define HID 32
#define TX 32
#define TY 16

typedef _Float16 f16x8 __attribute__((ext_vector_type(8)));
typedef float f32x4 __attribute__((ext_vector_type(4)));
typedef uint32_t u32x4 __attribute__((ext_vector_type(4)));

__host__ __device__ inline uint32_t rotl32(uint32_t x, int n) {
  return (x << n) | (x >> (32 - n));
}

__host__ __device__ inline void tf2x32(uint32_t k0, uint32_t k1,
                                       uint32_t x0, uint32_t x1,
                                       uint32_t& o0, uint32_t& o1) {
  uint32_t ks0 = k0, ks1 = k1, ks2 = k0 ^ k1 ^ 0x1BD11BDAu;
  x0 += ks0; x1 += ks1;
#define TFR(r) { x0 += x1; x1 = rotl32(x1, (r)); x1 ^= x0; }
  TFR(13) TFR(15) TFR(26) TFR(6)  x0 += ks1; x1 += ks2 + 1u;
  TFR(17) TFR(29) TFR(16) TFR(24) x0 += ks2; x1 += ks0 + 2u;
  TFR(13) TFR(15) TFR(26) TFR(6)  x0 += ks0; x1 += ks1 + 3u;
  TFR(17) TFR(29) TFR(16) TFR(24) x0 += ks1; x1 += ks2 + 4u;
  TFR(13) TFR(15) TFR(26) TFR(6)  x0 += ks2; x1 += ks0 + 5u;
#undef TFR
  o0 = x0; o1 = x1;
}

// gelu(x) = 0.5x + 0.5|x|*erf(|x|/sqrt2); erf via A&S 7.1.26 branchless, |err|<=1.5e-7.
__device__ inline float gelu_fast(float x) {
  const float ax = __builtin_fabsf(x);
  const float ay = 0.70710678118654752f * ax;
  const float t = __builtin_amdgcn_rcpf(fmaf(0.3275911f, ay, 1.0f));
  float p = fmaf(1.061405429f, t, -1.453152027f);
  p = fmaf(p, t, 1.421413741f);
  p = fmaf(p, t, -0.284496736f);
  p = fmaf(p, t, 0.254829592f);
  p *= t;
  const float e = __expf(-ay * ay);
  const float erfv = fmaf(-p, e, 1.0f);
  return fmaf(0.5f * ax, erfv, 0.5f * x);
}

// ---- bilinear upsample 8x8 -> 1024x1024, NHWC fp32 out ----
__global__ void init_kernel(const float* __restrict__ seed, float* __restrict__ dst) {
  int p = blockIdx.x * blockDim.x + threadIdx.x;
  if (p >= HH * WW) return;
  int y = p >> 10, x = p & 1023;
  float fy = (y + 0.5f) * (8.0f / HH) - 0.5f;
  float fx = (x + 0.5f) * (8.0f / WW) - 0.5f;
  int y0 = (int)floorf(fy); float wy = fy - (float)y0;
  int x0 = (int)floorf(fx); float wx = fx - (float)x0;
  int y0c = min(max(y0, 0), 7), y1c = min(max(y0 + 1, 0), 7);
  int x0c = min(max(x0, 0), 7), x1c = min(max(x0 + 1, 0), 7);
  float vals[8];
#pragma unroll
  for (int c = 0; c < SD; ++c) {
    const float* s = seed + c * 64;
    float v00 = s[y0c * 8 + x0c], v01 = s[y0c * 8 + x1c];
    float v10 = s[y1c * 8 + x0c], v11 = s[y1c * 8 + x1c];
    float v0 = v00 + (v01 - v00) * wx;
    float v1 = v10 + (v11 - v10) * wx;
    vals[c] = v0 + (v1 - v0) * wy;
  }
  f32x4 lo = {vals[0], vals[1], vals[2], vals[3]};
  f32x4 hi = {vals[4], vals[5], vals[6], vals[7]};
  *(f32x4*)(dst + (size_t)p * 8) = lo;
  *(f32x4*)(dst + (size_t)p * 8 + 4) = hi;
}

// ---- pack W1 (A-operand frags) and W2 (B-operand, k''-order) ----
// W1f: row n = nt*16+(lane&15) [out-ch], k = kc*32+(lane>>4)*8+j, k=tap*8+c -> tap=kc*4+q, c=j
// W2f: row n = lane&15 [out-ch, <8 valid], k'' = (lane>>4)*8+jj,
//      channel(k'') = (lane>>4)*4 + (jj&3) + ((jj>>2)<<4)
__global__ void prep_kernel(const float* __restrict__ W1, const float* __restrict__ W2,
                            _Float16* __restrict__ w1f, _Float16* __restrict__ w2f) {
  int tid = threadIdx.x;
  for (int i = tid; i < 2 * 3 * 64; i += 256) {
    int nt = i / 192, rem = i % 192;
    int kc = rem / 64, lane = rem % 64;
    int n = nt * 16 + (lane & 15);
    int tap = kc * 4 + (lane >> 4);
#pragma unroll
    for (int j = 0; j < 8; ++j) {
      float v = (tap < 9) ? W1[(n * SD + j) * 9 + tap] : 0.0f;
      w1f[i * 8 + j] = (_Float16)v;
    }
  }
  if (tid < 64) {
    int n = tid & 15, qk = tid >> 4;
#pragma unroll
    for (int jj = 0; jj < 8; ++jj) {
      int ch = qk * 4 + (jj & 3) + ((jj >> 2) << 4);
      float v = (n < 8) ? W2[n * HID + ch] : 0.0f;
      w2f[tid * 8 + jj] = (_Float16)v;
    }
  }
}

// ---- fused NCA step: one barrier; dx via wave-local LDS; coalesced update ----
__global__ __launch_bounds__(256) void step_kernel(
    const float* __restrict__ src, float* __restrict__ dst,
    const _Float16* __restrict__ w1f, const _Float16* __restrict__ w2f,
    const float* __restrict__ b1, const float* __restrict__ b2,
    uint32_t key0, uint32_t key1) {
  __shared__ _Float16 tile[(TY + 2) * (TX + 2) * SD];   // NHWC f16, halo +1 (9792 B)
  __shared__ float dxw[4][128 * 8];                     // per-wave dx, [px][ch] (16 KB)

  const int tid = threadIdx.x;
  const int bx = blockIdx.x, by = blockIdx.y;
  const int lane = tid & 63, w = tid >> 6;
  const int m = lane & 15, q = lane >> 4;

  // ---- weight fragments + biases (global, L1-hot) ----
  f16x8 af[2][3];
#pragma unroll
  for (int nt = 0; nt < 2; ++nt)
#pragma unroll
    for (int kc = 0; kc < 3; ++kc)
      af[nt][kc] = *(const f16x8*)(w1f + ((nt * 3 + kc) * 64 + lane) * 8);
  const f16x8 w2fr = *(const f16x8*)(w2f + lane * 8);
  const f32x4 b1q0 = *(const f32x4*)(b1 + q * 4);        // ch q*4+r
  const f32x4 b1q1 = *(const f32x4*)(b1 + 16 + q * 4);   // ch 16+q*4+r
  const float b2v = b2[m & 7];

  // ---- stage fp32 NHWC -> f16 NHWC LDS tile (zero pad outside) ----
  for (int i = tid; i < (TY + 2) * (TX + 2); i += 256) {
    int ly = i / (TX + 2), lx = i % (TX + 2);
    int gy = by * TY + ly - 1, gx = bx * TX + lx - 1;
    f16x8 v;
#pragma unroll
    for (int j = 0; j < 8; ++j) v[j] = (_Float16)0.0f;
    if ((unsigned)gy < HH && (unsigned)gx < WW) {
      const float* xp = src + (size_t)(gy * WW + gx) * 8;
      f32x4 lo = *(const f32x4*)xp;
      f32x4 hi = *(const f32x4*)(xp + 4);
#pragma unroll
      for (int j = 0; j < 4; ++j) { v[j] = (_Float16)lo[j]; v[4 + j] = (_Float16)hi[j]; }
    }
    *(f16x8*)&tile[i * 8] = v;
  }

  // ---- threefry masks for this thread's 2 update pixels (wave-local mapping) ----
  // thread handles block-pixels p = w*128 + half*64 + lane
  float maskf[2];
#pragma unroll
  for (int half = 0; half < 2; ++half) {
    const int p = w * 128 + half * 64 + lane;
    const uint32_t gp = (uint32_t)((by * TY + (p >> 5)) * WW + bx * TX + (p & 31));
    uint32_t r0, r1;
    tf2x32(key0, key1, 0u, gp, r0, r1);
    maskf[half] = (((r0 ^ r1) >> 9) > 0x400000u) ? 0.1f : 0.0f;  // 0.1*mask folded
  }
  __syncthreads();

  // per-lane B1 (pixel) base pointers for the 3 K-chunks (taps 9..11: zero A-rows, clamp addr)
  const _Float16* bp_[3];
#pragma unroll
  for (int kc = 0; kc < 3; ++kc) {
    int t = kc * 4 + q; if (t > 8) t = 0;
    bp_[kc] = &tile[((t / 3) * (TX + 2) + m + (t % 3)) * 8];
  }

#pragma unroll
  for (int r4 = 0; r4 < 4; ++r4) {
    const int y = w * 4 + r4;                       // local row 0..15, wave-uniform
#pragma unroll
    for (int xh = 0; xh < 2; ++xh) {
      const int x0 = xh * 16;
      f32x4 acc0 = b1q0, acc1 = b1q1;               // bias folded into C
#pragma unroll
      for (int kc = 0; kc < 3; ++kc) {
        const f16x8 bfrag = *(const f16x8*)(bp_[kc] + (y * (TX + 2) + x0) * 8);
        acc0 = __builtin_amdgcn_mfma_f32_16x16x32_f16(af[0][kc], bfrag, acc0, 0, 0, 0);
        acc1 = __builtin_amdgcn_mfma_f32_16x16x32_f16(af[1][kc], bfrag, acc1, 0, 0, 0);
      }
      // lane holds hidden ch {q*4+r} (acc0) and {16+q*4+r} (acc1) of pixel x0+m.
      u32x4 a2d;
      {
        float g0 = gelu_fast(acc0[0]), g1 = gelu_fast(acc0[1]);
        float g2 = gelu_fast(acc0[2]), g3 = gelu_fast(acc0[3]);
        float g4 = gelu_fast(acc1[0]), g5 = gelu_fast(acc1[1]);
        float g6 = gelu_fast(acc1[2]), g7 = gelu_fast(acc1[3]);
        a2d[0] = __builtin_bit_cast(uint32_t, __builtin_amdgcn_cvt_pkrtz(g0, g1));
        a2d[1] = __builtin_bit_cast(uint32_t, __builtin_amdgcn_cvt_pkrtz(g2, g3));
        a2d[2] = __builtin_bit_cast(uint32_t, __builtin_amdgcn_cvt_pkrtz(g4, g5));
        a2d[3] = __builtin_bit_cast(uint32_t, __builtin_amdgcn_cvt_pkrtz(g6, g7));
      }
      const f16x8 a2 = __builtin_bit_cast(f16x8, a2d);
      f32x4 acc2 = {b2v, b2v, b2v, b2v};
      acc2 = __builtin_amdgcn_mfma_f32_16x16x32_f16(a2, w2fr, acc2, 0, 0, 0);
      // D2: lane&15 = out-ch (m<8 valid), regs = pixels x0+q*4+r -> wave-local LDS stage
      if (m < 8) {
        float* wp = &dxw[w][(r4 * 32 + x0 + q * 4) * 8 + m];
        wp[0]  = acc2[0];
        wp[8]  = acc2[1];
        wp[16] = acc2[2];
        wp[24] = acc2[3];
      }
    }
  }

  // ---- wave-local coalesced update: x_new = x + dx*(0.1*mask) ----
  // (intra-wave ds_write->ds_read: in-order LDS pipe + lgkmcnt, no barrier needed)
#pragma unroll
  for (int half = 0; half < 2; ++half) {
    const int pw = half * 64 + lane;                // pixel within wave region, 0..127
    const int p = w * 128 + pw;
    const uint32_t gp = (uint32_t)((by * TY + (p >> 5)) * WW + bx * TX + (p & 31));
    const float mk = maskf[half];
    const float* dxp = &dxw[w][pw * 8];
    f32x4 d0 = *(const f32x4*)dxp;
    f32x4 d1 = *(const f32x4*)(dxp + 4);
    const float* xp = src + (size_t)gp * 8;
    f32x4 lo = *(const f32x4*)xp;
    f32x4 hi = *(const f32x4*)(xp + 4);
#pragma unroll
    for (int j = 0; j < 4; ++j) {
      lo[j] = fmaf(d0[j], mk, lo[j]);
      hi[j] = fmaf(d1[j], mk, hi[j]);
    }
    float* op = dst + (size_t)gp * 8;
    *(f32x4*)op = lo;
    *(f32x4*)(op + 4) = hi;
  }
}

// ---- projection: out[p] = bp + sum_c x[p][c]*Wp[c] (NHWC) ----
__global__ void proj_kernel(const float* __restrict__ x,
                            const float* __restrict__ Wp,
                            const float* __restrict__ bp,
                            float* __restrict__ out) {
  int p = blockIdx.x * blockDim.x + threadIdx.x;
  if (p >= HH * WW) return;
  const float* xp = x + (size_t)p * 8;
  f32x4 lo = *(const f32x4*)xp;
  f32x4 hi = *(const f32x4*)(xp + 4);
  float acc = bp[0];
#pragma unroll
  for (int c = 0; c < 4; ++c) acc = fmaf(lo[c], Wp[c], acc);
#pragma unroll
  for (int c = 0; c < 4; ++c) acc = fmaf(hi[c], Wp[4 + c], acc);
  out[p] = acc;
}

extern "C" void kernel_launch(void* const* d_in, const int* in_sizes, int n_in,
                              void* d_out, int out_size, void* d_ws, size_t ws_size,
                              hipStream_t stream) {
  (void)in_sizes; (void)n_in; (void)out_size; (void)ws_size;
  const float* seed = (const float*)d_in[0];
  const float* W1   = (const float*)d_in[1];
  const float* b1   = (const float*)d_in[2];
  const float* W2   = (const float*)d_in[3];
  const float* b2   = (const float*)d_in[4];
  const float* Wp   = (const float*)d_in[5];
  const float* bp   = (const float*)d_in[6];
  float* out  = (float*)d_out;
  float* buf0 = (float*)d_ws;
  float* buf1 = buf0 + (size_t)SD * HH * WW;
  _Float16* w1f = (_Float16*)(buf1 + (size_t)SD * HH * WW);
  _Float16* w2f = w1f + 2 * 3 * 64 * 8;

  // 64 subkeys of jax.random.split(jax.random.key(42), 64) (raw pairs, no xor)
  uint32_t ka[64], kb[64];
  for (int i = 0; i < 64; ++i) tf2x32(0u, 42u, 0u, (uint32_t)i, ka[i], kb[i]);

  hipLaunchKernelGGL(prep_kernel, dim3(1), dim3(256), 0, stream, W1, W2, w1f, w2f);
  hipLaunchKernelGGL(init_kernel, dim3((HH * WW) / 256), dim3(256), 0, stream, seed, buf0);

  dim3 grid(WW / TX, HH / TY);
  float* s = buf0; float* d = buf1;
  for (int i = 0; i < 64; ++i) {
    hipLaunchKernelGGL(step_kernel, grid, dim3(256), 0, stream,
                       s, d, w1f, w2f, b1, b2, ka[i], kb[i]);
    float* t = s; s = d; d = t;
  }
  hipLaunchKernelGGL(proj_kernel, dim3((HH * WW) / 256), dim3(256), 0, stream,
                     s, Wp, bp, out);
}